// Round 1
// 783.343 us; speedup vs baseline: 1.1836x; 1.1836x over previous
//
#include <hip/hip_runtime.h>
#include <stdint.h>

typedef unsigned short u16;
typedef __attribute__((ext_vector_type(8))) short short8;
typedef __attribute__((ext_vector_type(4))) float floatx4;

#define DEVFN static __device__ __forceinline__

DEVFN float bf2f(u16 u) { unsigned int x = ((unsigned int)u) << 16; float f; __builtin_memcpy(&f, &x, 4); return f; }
DEVFN u16 f2bf(float f) { unsigned int x; __builtin_memcpy(&x, &f, 4); x = (x + 0x7FFFu + ((x >> 16) & 1u)) >> 16; return (u16)x; }
DEVFN float san(float v) { return (v == v) ? v : 0.0f; }

DEVFN void gld16(const u16* g, u16* l)
{
    __builtin_amdgcn_global_load_lds(
        (const __attribute__((address_space(1))) unsigned int*)g,
        (__attribute__((address_space(3))) unsigned int*)l,
        16, 0, 0);
}

static constexpr int BB = 2048;
static constexpr int NTAIL = 20000;
static constexpr int EE = 512;
static constexpr int CC = 128;

// ---------------------------------------------------------------------------
// Small NT GEMM (1 wave): C[M,N] = A[M,K] * B[N,K]^T (+bias) (relu).
// Kept for the B=2048 MLP chain and as FUSEX fallback for Wm.
// ---------------------------------------------------------------------------
template<int MT, int NT, bool RELU, bool BIAS, bool OUTBF, bool ATOMIC, bool FUSEX>
__global__ __launch_bounds__(64)
void gemm_nt(const u16* __restrict__ A, const u16* __restrict__ Bm,
             void* __restrict__ Cout, const float* __restrict__ bias,
             const u16* __restrict__ rsp, const u16* __restrict__ hap,
             int M, int N, int K, int lda, int klen)
{
    const int lane = threadIdx.x;
    const int r = lane & 15, q = lane >> 4;
    const int m0 = blockIdx.x * (MT * 16);
    const int n0 = blockIdx.y * (NT * 16);
    int k0 = 0, kend = K;
    if (ATOMIC) { k0 = blockIdx.z * klen; kend = k0 + klen; }

    int arow[MT];
    size_t abase[MT];
    size_t bbase[NT];
#pragma unroll
    for (int mt = 0; mt < MT; ++mt) {
        int row = m0 + mt * 16 + r; if (row > M - 1) row = M - 1;
        arow[mt] = row;
        abase[mt] = (size_t)row * (size_t)lda;
    }
#pragma unroll
    for (int nt = 0; nt < NT; ++nt) {
        int row = n0 + nt * 16 + r; if (row > N - 1) row = N - 1;
        bbase[nt] = (size_t)row * (size_t)K;
    }

    floatx4 acc[MT][NT];
#pragma unroll
    for (int mt = 0; mt < MT; ++mt)
#pragma unroll
        for (int nt = 0; nt < NT; ++nt) acc[mt][nt] = (floatx4)0.0f;

    for (int k = k0; k < kend; k += 32) {
        const int ko = k + q * 8;
        short8 af[MT], bfr[NT];
        if (FUSEX) {
            const int e = ko >> 7, c0 = ko & 127;
#pragma unroll
            for (int mt = 0; mt < MT; ++mt) {
                const float rsv = bf2f(rsp[arow[mt] * 128 + e]);
                short8 hv = *reinterpret_cast<const short8*>(hap + arow[mt] * 128 + c0);
                short8 t;
#pragma unroll
                for (int j = 0; j < 8; ++j) t[j] = (short)f2bf(rsv * bf2f((u16)hv[j]));
                af[mt] = t;
            }
        } else {
#pragma unroll
            for (int mt = 0; mt < MT; ++mt)
                af[mt] = *reinterpret_cast<const short8*>(A + abase[mt] + ko);
        }
#pragma unroll
        for (int nt = 0; nt < NT; ++nt)
            bfr[nt] = *reinterpret_cast<const short8*>(Bm + bbase[nt] + ko);
#pragma unroll
        for (int mt = 0; mt < MT; ++mt)
#pragma unroll
            for (int nt = 0; nt < NT; ++nt)
                acc[mt][nt] = __builtin_amdgcn_mfma_f32_16x16x32_bf16(af[mt], bfr[nt], acc[mt][nt], 0, 0, 0);
    }

#pragma unroll
    for (int nt = 0; nt < NT; ++nt) {
        const int col = n0 + nt * 16 + r;
        if (col >= N) continue;
        float bv = 0.0f;
        if (BIAS) bv = san(bias[col]);
#pragma unroll
        for (int mt = 0; mt < MT; ++mt) {
#pragma unroll
            for (int rr = 0; rr < 4; ++rr) {
                const int row = m0 + mt * 16 + q * 4 + rr;
                if (row >= M) continue;
                float v = acc[mt][nt][rr] + bv;
                if (RELU) v = fmaxf(v, 0.0f);
                const size_t idx = (size_t)row * (size_t)N + col;
                if (ATOMIC)      atomicAdd((float*)Cout + idx, v);
                else if (OUTBF)  ((u16*)Cout)[idx] = f2bf(v);
                else             ((float*)Cout)[idx] = v;
            }
        }
    }
}

// ---------------------------------------------------------------------------
// Heavy NT GEMM (m97 structure): 256 threads / 4 waves (2x2), 128x128 tile,
// K-step 32, global_load_lds(16B) staging, 2 barriers per k-step.
// C[M,N] = A[M,K] * B[N,K]^T (+bias)(relu). lda = A row stride, B stride = K.
// ---------------------------------------------------------------------------
template<bool RELU, bool BIAS, bool OUTBF, bool ATOMIC>
__global__ __launch_bounds__(256)
void gemm128(const u16* __restrict__ A, const u16* __restrict__ Bm,
             void* __restrict__ Cout, const float* __restrict__ bias,
             int M, int N, int K, int lda, int klen)
{
    __shared__ u16 As[128 * 32];
    __shared__ u16 Bs[128 * 32];
    const int t = threadIdx.x;
    const int lane = t & 63;
    const int wave = t >> 6;
    const int wr = wave >> 1, wc = wave & 1;
    const int r = lane & 15, q = lane >> 4;
    const int m0 = blockIdx.x * 128;
    const int n0 = blockIdx.y * 128;
    int k0 = 0, kend = K;
    if (ATOMIC) { k0 = blockIdx.z * klen; kend = k0 + klen; }

    // staging: each wave stages 16 contiguous rows per round (lane l -> row
    // +l/4, col8 (l%4)*8); LDS dest is wave-uniform base + lane*16 (HW rule).
    const int sr = lane >> 2;
    const int sc = (lane & 3) * 8;
    int ar0 = m0 + wave * 16 + sr;       if (ar0 > M - 1) ar0 = M - 1;
    int ar1 = m0 + 64 + wave * 16 + sr;  if (ar1 > M - 1) ar1 = M - 1;
    int br0 = n0 + wave * 16 + sr;       if (br0 > N - 1) br0 = N - 1;
    int br1 = n0 + 64 + wave * 16 + sr;  if (br1 > N - 1) br1 = N - 1;

    const u16* aS0 = A + (size_t)ar0 * (size_t)lda + sc;
    const u16* aS1 = A + (size_t)ar1 * (size_t)lda + sc;
    const u16* bS0 = Bm + (size_t)br0 * (size_t)K + sc;
    const u16* bS1 = Bm + (size_t)br1 * (size_t)K + sc;
    u16* aD0 = As + (wave * 16) * 32;
    u16* aD1 = As + (64 + wave * 16) * 32;
    u16* bD0 = Bs + (wave * 16) * 32;
    u16* bD1 = Bs + (64 + wave * 16) * 32;

    floatx4 acc[4][4];
#pragma unroll
    for (int i = 0; i < 4; ++i)
#pragma unroll
        for (int j = 0; j < 4; ++j) acc[i][j] = (floatx4)0.0f;

    const int aoff = (wr * 64 + r) * 32 + q * 8;
    const int boff = (wc * 64 + r) * 32 + q * 8;

    for (int k = k0; k < kend; k += 32) {
        gld16(aS0 + k, aD0);
        gld16(aS1 + k, aD1);
        gld16(bS0 + k, bD0);
        gld16(bS1 + k, bD1);
        __syncthreads();   // drains vmcnt (global_load_lds) + lgkmcnt
        short8 af[4], bfr[4];
#pragma unroll
        for (int mt = 0; mt < 4; ++mt)
            af[mt] = *reinterpret_cast<const short8*>(As + aoff + mt * (16 * 32));
#pragma unroll
        for (int nt = 0; nt < 4; ++nt)
            bfr[nt] = *reinterpret_cast<const short8*>(Bs + boff + nt * (16 * 32));
#pragma unroll
        for (int mt = 0; mt < 4; ++mt)
#pragma unroll
            for (int nt = 0; nt < 4; ++nt)
                acc[mt][nt] = __builtin_amdgcn_mfma_f32_16x16x32_bf16(af[mt], bfr[nt], acc[mt][nt], 0, 0, 0);
        __syncthreads();
    }

#pragma unroll
    for (int nt = 0; nt < 4; ++nt) {
        const int col = n0 + wc * 64 + nt * 16 + r;
        if (col >= N) continue;
        float bv = 0.0f;
        if (BIAS) bv = san(bias[col]);
#pragma unroll
        for (int mt = 0; mt < 4; ++mt) {
#pragma unroll
            for (int rr = 0; rr < 4; ++rr) {
                const int row = m0 + wr * 64 + mt * 16 + q * 4 + rr;
                if (row >= M) continue;
                float v = acc[mt][nt][rr] + bv;
                if (RELU) v = fmaxf(v, 0.0f);
                const size_t idx = (size_t)row * (size_t)N + col;
                if (ATOMIC)      atomicAdd((float*)Cout + idx, v);
                else if (OUTBF)  ((u16*)Cout)[idx] = f2bf(v);
                else             ((float*)Cout)[idx] = v;
            }
        }
    }
}

// ---------------------------------------------------------------------------
// Akron[b, e*128+c] = rs[b,e] * ha[b,c]   (bf16, 8 elems/thread)
// ---------------------------------------------------------------------------
__global__ __launch_bounds__(256) void kron_rs_ha(const u16* __restrict__ rs,
                                                  const u16* __restrict__ ha,
                                                  u16* __restrict__ out)
{
    int id = blockIdx.x * 256 + threadIdx.x;      // BB*2048 threads
    int b = id >> 11;
    int j = id & 2047;
    int e = j >> 4;
    int c0 = (j & 15) << 3;
    float rv = bf2f(rs[b * 128 + e]);
    short8 hv = *reinterpret_cast<const short8*>(ha + b * 128 + c0);
    short8 o;
#pragma unroll
    for (int i = 0; i < 8; ++i) o[i] = (short)f2bf(rv * bf2f((u16)hv[i]));
    *reinterpret_cast<short8*>(out + (size_t)b * 16384 + (size_t)j * 8) = o;
}

// fp32 -> bf16 cast, 8 elems/thread (NaN-sanitized)
__global__ void cast8_f32_bf16(const float* __restrict__ in, u16* __restrict__ out, int n8)
{
    int id = blockIdx.x * 256 + threadIdx.x;
    if (id >= n8) return;
    const floatx4* p = reinterpret_cast<const floatx4*>(in) + (size_t)id * 2;
    floatx4 a = p[0], b = p[1];
    short8 o;
#pragma unroll
    for (int i = 0; i < 4; ++i) { o[i] = (short)f2bf(san(a[i])); o[i + 4] = (short)f2bf(san(b[i])); }
    *reinterpret_cast<short8*>(out + (size_t)id * 8) = o;
}

// ---------------------------------------------------------------------------
// Batched weight transpose+cast: all 12 weight matrices in one launch.
// in[R,C] fp32 -> out[C,R] bf16, 32x32 tiles.
// ---------------------------------------------------------------------------
struct TJobs {
    const float* in[12];
    u16* out[12];
    int R[12], C[12];
    int tstart[13];
};

__global__ __launch_bounds__(256) void transpose_multi(TJobs j)
{
    __shared__ float tile[32][33];
    int tb = blockIdx.x;
    int job = 0;
    while (job < 11 && tb >= j.tstart[job + 1]) ++job;
    int local = tb - j.tstart[job];
    const int R = j.R[job], C = j.C[job];
    const int cb = (C + 31) >> 5;
    const int bx = local % cb, by = local / cb;
    const float* in = j.in[job];
    u16* out = j.out[job];
    const int c0 = bx * 32, r0 = by * 32;
    const int tx = threadIdx.x, ty = threadIdx.y;
#pragma unroll
    for (int i = 0; i < 32; i += 8) {
        int rr = r0 + ty + i, cc = c0 + tx;
        if (rr < R && cc < C) tile[ty + i][tx] = in[(size_t)rr * C + cc];
    }
    __syncthreads();
#pragma unroll
    for (int i = 0; i < 32; i += 8) {
        int orow = c0 + ty + i, ocol = r0 + tx;
        if (orow < C && ocol < R) out[(size_t)orow * R + ocol] = f2bf(san(tile[tx][ty + i]));
    }
}

// concat [head | relation] fp32 -> hr_in [B,1024] bf16
__global__ void concat_hr(const float* __restrict__ h, const float* __restrict__ r, u16* __restrict__ out)
{
    int id = blockIdx.x * 256 + threadIdx.x;
    int b = id >> 10, j = id & 1023;
    float v = (j < 512) ? h[(b << 9) + j] : r[(b << 9) + j - 512];
    out[id] = f2bf(san(v));
}

// BatchNorm batch stats; X [R,128] fp32 -> mean[128], rstd[128]
__global__ __launch_bounds__(256) void bn_stats(const float* __restrict__ X, int R,
                                                float* __restrict__ mean, float* __restrict__ rstd)
{
    __shared__ float ss[256], sq[256];
    int c = blockIdx.x, t = threadIdx.x;
    float s = 0.f, s2 = 0.f;
    for (int rr = t; rr < R; rr += 256) { float v = X[(size_t)rr * 128 + c]; s += v; s2 += v * v; }
    ss[t] = s; sq[t] = s2; __syncthreads();
    for (int off = 128; off > 0; off >>= 1) {
        if (t < off) { ss[t] += ss[t + off]; sq[t] += sq[t + off]; }
        __syncthreads();
    }
    if (t == 0) {
        float m = ss[0] / R;
        float var = fmaxf(sq[0] / R - m * m, 0.0f);
        mean[c] = m;
        rstd[c] = 1.0f / sqrtf(var + 1e-5f);
    }
}

// y = g*(x-m)*rstd + b, g/b fp32, bf16 out
__global__ void bn_apply(const float* __restrict__ X, const float* __restrict__ mean,
                         const float* __restrict__ rstd, const float* __restrict__ g,
                         const float* __restrict__ b, u16* __restrict__ out, int n)
{
    int id = blockIdx.x * 256 + threadIdx.x;
    if (id >= n) return;
    int c = id & 127;
    float v = (X[id] - mean[c]) * rstd[c] * san(g[c]) + san(b[c]);
    out[id] = f2bf(v);
}

__global__ void zero_f32(float* __restrict__ p, int n)
{
    int id = blockIdx.x * 256 + threadIdx.x;
    if (id < n) p[id] = 0.0f;
}

// fused soft top-k over two tensors: rows [0,R0) from X0, rest from X1
__global__ __launch_bounds__(64) void soft_topk2(const float* __restrict__ X0, u16* __restrict__ O0, int R0,
                                                 const float* __restrict__ X1, u16* __restrict__ O1)
{
    int row = blockIdx.x, lane = threadIdx.x;
    const float* x; u16* o;
    if (row < R0) { x = X0 + (size_t)row * 128; o = O0 + (size_t)row * 128; }
    else          { x = X1 + (size_t)(row - R0) * 128; o = O1 + (size_t)(row - R0) * 128; }
    float v0 = x[lane], v1 = x[lane + 64];
    float w0 = v0, w1 = v1;
    float thr = 0.f;
    for (int it = 0; it < 10; ++it) {
        float m = fmaxf(w0, w1);
#pragma unroll
        for (int off = 32; off > 0; off >>= 1) m = fmaxf(m, __shfl_xor(m, off));
        if (it == 9) { thr = m; break; }
        unsigned long long msk = __ballot((w0 == m) || (w1 == m));
        if (msk) {
            int first = (int)__builtin_ctzll(msk);
            if (lane == first) {
                if (w0 == m) w0 = -__builtin_inff(); else w1 = -__builtin_inff();
            }
        }
    }
    float z0 = 1.f / (1.f + expf(-(v0 - thr) * 2.f));
    float z1 = 1.f / (1.f + expf(-(v1 - thr) * 2.f));
    o[lane]      = f2bf(z0 * v0);
    o[lane + 64] = f2bf(z1 * v1);
}

// inter[b,d] = sum_c hrm[b,c] * tanh(codebook[rel[b],c,d]) ; codebook fp32
__global__ __launch_bounds__(128) void inter_kernel(const u16* __restrict__ hrm,
                                                    const float* __restrict__ codebook,
                                                    const int* __restrict__ relidx,
                                                    u16* __restrict__ out)
{
    int b = blockIdx.x, d = threadIdx.x;
    int rel = relidx[b];
    const float* cb = codebook + (size_t)rel * (128 * 128);
    const u16* hr = hrm + (size_t)b * 128;
    float s = 0.f;
    for (int c = 0; c < 128; ++c)
        s += bf2f(hr[c]) * tanhf(san(cb[c * 128 + d]));
    out[(size_t)b * 128 + d] = f2bf(s);
}

// ---------------------------------------------------------------------------
extern "C" void kernel_launch(void* const* d_in, const int* in_sizes, int n_in,
                              void* d_out, int out_size, void* d_ws, size_t ws_size,
                              hipStream_t stream)
{
    (void)in_sizes; (void)n_in; (void)out_size;

    const float* head    = (const float*)d_in[0];
    const float* relv    = (const float*)d_in[1];
    const int*   relidx  = (const int*)d_in[2];
    const float* tail    = (const float*)d_in[3];
    const float* codebook= (const float*)d_in[5];
    const float* core    = (const float*)d_in[6];
    const float* hsw1 = (const float*)d_in[7],  *hsb1 = (const float*)d_in[8];
    const float* hsw2 = (const float*)d_in[9],  *hsb2 = (const float*)d_in[10];
    const float* rsw1 = (const float*)d_in[11], *rsb1 = (const float*)d_in[12];
    const float* rsw2 = (const float*)d_in[13], *rsb2 = (const float*)d_in[14];
    const float* tsw1 = (const float*)d_in[15], *tsb1 = (const float*)d_in[16];
    const float* tsw2 = (const float*)d_in[17], *tsb2 = (const float*)d_in[18];
    const float* bn0g = (const float*)d_in[19], *bn0b = (const float*)d_in[20];
    const float* bn1g = (const float*)d_in[21], *bn1b = (const float*)d_in[22];
    const float* hrw1 = (const float*)d_in[23], *hrb1 = (const float*)d_in[24];
    const float* hrw2 = (const float*)d_in[25], *hrb2 = (const float*)d_in[26];
    const float* hrw3 = (const float*)d_in[27], *hrb3 = (const float*)d_in[28];
    const float* taw1 = (const float*)d_in[29], *tab1 = (const float*)d_in[30];
    const float* taw2 = (const float*)d_in[31], *tab2 = (const float*)d_in[32];

    float* out_tucker = (float*)d_out;
    float* out_poss   = out_tucker + (size_t)BB * NTAIL;

    // ---- workspace layout ----
    char* ws = (char*)d_ws;
    size_t off = 0;
    auto alloc = [&](size_t bytes) -> char* {
        char* p = ws + off;
        off += (bytes + 255) & ~(size_t)255;
        return p;
    };

    float* hs_f   = (float*)alloc((size_t)BB * CC * 4);
    float* hra_f  = (float*)alloc((size_t)BB * CC * 4);
    float* Wm_pre = (float*)alloc((size_t)BB * CC * 4);
    float* mean0  = (float*)alloc(128 * 4);
    float* rstd0  = (float*)alloc(128 * 4);
    float* mean1  = (float*)alloc(128 * 4);
    float* rstd1  = (float*)alloc(128 * 4);

    u16* t_hid   = (u16*)alloc((size_t)NTAIL * EE * 2);   // [20000,512]
    u16* hr_in   = (u16*)alloc((size_t)BB * 1024 * 2);    // [2048,1024]; later tam
    u16* h_hid   = (u16*)alloc((size_t)BB * EE * 2);      // [2048,512]; later h1|h2
    u16* h1      = h_hid;
    u16* h2      = h_hid + (size_t)BB * 256;
    u16* tam_bf  = hr_in;                                  // [20000,128] = 5.12MB < 6MB
    u16* ts_bf   = (u16*)alloc((size_t)NTAIL * CC * 2);   // [20000,128]
    u16* tail_bf = (u16*)alloc((size_t)NTAIL * EE * 2);   // [20000,512]; later ta_f
    float* ta_f  = (float*)tail_bf;
    u16* rs_bf   = (u16*)alloc((size_t)BB * CC * 2);
    u16* ha_bf   = (u16*)alloc((size_t)BB * CC * 2);
    u16* Wm_bf   = (u16*)alloc((size_t)BB * CC * 2);
    u16* hrm_bf  = (u16*)alloc((size_t)BB * CC * 2);
    u16* inter_bf= (u16*)alloc((size_t)BB * CC * 2);

    u16* hsw1t = (u16*)alloc((size_t)EE * EE * 2);
    u16* hsw2t = (u16*)alloc((size_t)CC * EE * 2);
    u16* rsw1t = (u16*)alloc((size_t)EE * EE * 2);
    u16* rsw2t = (u16*)alloc((size_t)CC * EE * 2);
    u16* tsw1t = (u16*)alloc((size_t)EE * EE * 2);
    u16* tsw2t = (u16*)alloc((size_t)CC * EE * 2);
    u16* taw1t = (u16*)alloc((size_t)EE * EE * 2);
    u16* taw2t = (u16*)alloc((size_t)CC * EE * 2);
    u16* hrw1t = (u16*)alloc((size_t)256 * 1024 * 2);
    u16* hrw2t = (u16*)alloc((size_t)256 * 256 * 2);
    u16* hrw3t = (u16*)alloc((size_t)128 * 256 * 2);
    u16* core_t = (u16*)alloc((size_t)CC * 16384 * 2);

    const size_t off_base = off;
    if (off_base > ws_size) return;  // diagnostic: zero output => ws too small

    // optional 64 MB Akron buffer (rs (x) ha materialized); fallback = FUSEX
    u16* akron = (u16*)alloc((size_t)BB * 16384 * 2);
    const bool use_akron = (off <= ws_size);

    // ---- all 12 weight transposes in ONE launch ----
    TJobs tj;
    int ti = 0, tcum = 0;
    auto addT = [&](const float* in, u16* outp, int R, int Cc) {
        tj.in[ti] = in; tj.out[ti] = outp; tj.R[ti] = R; tj.C[ti] = Cc;
        tj.tstart[ti] = tcum;
        tcum += ((Cc + 31) / 32) * ((R + 31) / 32);
        ++ti;
    };
    addT(hsw1, hsw1t, EE, EE);   addT(hsw2, hsw2t, EE, CC);
    addT(rsw1, rsw1t, EE, EE);   addT(rsw2, rsw2t, EE, CC);
    addT(tsw1, tsw1t, EE, EE);   addT(tsw2, tsw2t, EE, CC);
    addT(taw1, taw1t, EE, EE);   addT(taw2, taw2t, EE, CC);
    addT(hrw1, hrw1t, 2 * EE, 2 * CC);
    addT(hrw2, hrw2t, 2 * CC, 2 * CC);
    addT(hrw3, hrw3t, 2 * CC, CC);
    addT(core, core_t, CC * CC, CC);
    tj.tstart[12] = tcum;
    transpose_multi<<<tcum, dim3(32, 8), 0, stream>>>(tj);

    concat_hr<<<(BB * 1024) / 256, 256, 0, stream>>>(head, relv, hr_in);
    cast8_f32_bf16<<<(NTAIL * EE / 8) / 256, 256, 0, stream>>>(tail, tail_bf, NTAIL * EE / 8);

    // ---- B=2048 MLP chain (small 1-wave gemms; latency-tolerant sizes) ----
    gemm_nt<2, 2, true, true, true, false, false><<<dim3(BB / 32, EE / 32), 64, 0, stream>>>(
        hr_in, hsw1t, h_hid, hsb1, nullptr, nullptr, BB, EE, EE, 1024, 0);
    gemm_nt<2, 2, false, true, false, false, false><<<dim3(BB / 32, CC / 32), 64, 0, stream>>>(
        h_hid, hsw2t, hs_f, hsb2, nullptr, nullptr, BB, CC, EE, EE, 0);
    gemm_nt<2, 2, true, true, true, false, false><<<dim3(BB / 32, EE / 32), 64, 0, stream>>>(
        hr_in + 512, rsw1t, h_hid, rsb1, nullptr, nullptr, BB, EE, EE, 1024, 0);
    gemm_nt<2, 2, false, true, true, false, false><<<dim3(BB / 32, CC / 32), 64, 0, stream>>>(
        h_hid, rsw2t, rs_bf, rsb2, nullptr, nullptr, BB, CC, EE, EE, 0);

    // ---- heavy tail-side GEMMs: 128x128 LDS-staged structure ----
    gemm128<true, true, true, false><<<dim3(157, EE / 128), 256, 0, stream>>>(
        tail_bf, tsw1t, t_hid, tsb1, NTAIL, EE, EE, EE, 0);
    gemm128<false, true, true, false><<<dim3(157, 1), 256, 0, stream>>>(
        t_hid, tsw2t, ts_bf, tsb2, NTAIL, CC, EE, EE, 0);
    gemm128<true, true, true, false><<<dim3(157, EE / 128), 256, 0, stream>>>(
        tail_bf, taw1t, t_hid, tab1, NTAIL, EE, EE, EE, 0);
    // ta_f aliases tail_bf (tail_bf dead now)
    gemm128<false, true, false, false><<<dim3(157, 1), 256, 0, stream>>>(
        t_hid, taw2t, ta_f, tab2, NTAIL, CC, EE, EE, 0);

    // hr abstract chain (h1/h2 reuse h_hid; hr_in still live as input here)
    gemm_nt<2, 2, true, true, true, false, false><<<dim3(BB / 32, 256 / 32), 64, 0, stream>>>(
        hr_in, hrw1t, h1, hrb1, nullptr, nullptr, BB, 256, 1024, 1024, 0);
    gemm_nt<2, 2, true, true, true, false, false><<<dim3(BB / 32, 256 / 32), 64, 0, stream>>>(
        h1, hrw2t, h2, hrb2, nullptr, nullptr, BB, 256, 256, 256, 0);
    gemm_nt<2, 2, false, true, false, false, false><<<dim3(BB / 32, CC / 32), 64, 0, stream>>>(
        h2, hrw3t, hra_f, hrb3, nullptr, nullptr, BB, CC, 256, 256, 0);

    // ---- BN0 on hs -> ha (bf16) ----
    bn_stats<<<128, 256, 0, stream>>>(hs_f, BB, mean0, rstd0);
    bn_apply<<<(BB * CC) / 256, 256, 0, stream>>>(hs_f, mean0, rstd0, bn0g, bn0b, ha_bf, BB * CC);

    // ---- Wm_pre = (rs (x) ha) @ core2^T, split-K fp32 atomics ----
    zero_f32<<<(BB * CC) / 256, 256, 0, stream>>>(Wm_pre, BB * CC);
    if (use_akron) {
        kron_rs_ha<<<(BB * 2048) / 256, 256, 0, stream>>>(rs_bf, ha_bf, akron);
        gemm128<false, false, false, true><<<dim3(BB / 128, 1, 16), 256, 0, stream>>>(
            akron, core_t, Wm_pre, nullptr, BB, CC, 16384, 16384, 1024);
    } else {
        gemm_nt<2, 2, false, false, false, true, true><<<dim3(BB / 32, CC / 32, 8), 64, 0, stream>>>(
            nullptr, core_t, Wm_pre, nullptr, rs_bf, ha_bf, BB, CC, 16384, 16384, 16384 / 8);
    }

    // ---- BN1 -> Wm (bf16) ----
    bn_stats<<<128, 256, 0, stream>>>(Wm_pre, BB, mean1, rstd1);
    bn_apply<<<(BB * CC) / 256, 256, 0, stream>>>(Wm_pre, mean1, rstd1, bn1g, bn1b, Wm_bf, BB * CC);

    // ---- tucker_logits = Wm @ ts^T (fp32 out) ----
    gemm128<false, false, false, false><<<dim3(BB / 128, 157), 256, 0, stream>>>(
        Wm_bf, ts_bf, out_tucker, nullptr, BB, NTAIL, CC, CC, 0);

    // ---- soft top-k masks, fused (tam_bf reuses hr_in — hr_in/h_hid dead) ----
    soft_topk2<<<BB + NTAIL, 64, 0, stream>>>(hra_f, hrm_bf, BB, ta_f, tam_bf);

    // ---- inter = einsum(hrm, tanh(codebook[rel])) ----
    inter_kernel<<<BB, 128, 0, stream>>>(hrm_bf, codebook, relidx, inter_bf);

    // ---- possibility = inter @ tam^T (fp32 out) ----
    gemm128<false, false, false, false><<<dim3(BB / 128, 157), 256, 0, stream>>>(
        inter_bf, tam_bf, out_poss, nullptr, BB, NTAIL, CC, CC, 0);
}